// Round 8
// baseline (417.618 us; speedup 1.0000x reference)
//
#include <hip/hip_runtime.h>
#include <cstdint>

// LeNet-5 forward, B=16384. R8: 5 dispatches.
//   k_front: x -> (in-block transpose) -> C1+S2 MFMA -> S2P     (grid 1024)
//   k_c3   : S2P -> C3+S4 MFMA (row-reg cache, dual-A) -> S4H   (grid 1024)
//   k_c5 / k_f6 / k_rbf: verified R7 tail kernels.
// Workspace: S2P u32[588][16384] @ 0          (38,535,168)
//            S4H f16[400][16384] @ 38,535,168 (13,107,200)  peak 51.6 MB
//            H5P u32[60][16384]  @ 0          ( 3,932,160)  after c3 (S2P dead)
//            H6P u32[42][16384]  @ 4,194,304  ( 2,752,512)

typedef unsigned int u32;
typedef _Float16 f16x8 __attribute__((ext_vector_type(8)));
typedef float f32x4 __attribute__((ext_vector_type(4)));
typedef u32 u32x4 __attribute__((ext_vector_type(4)));

union U32H2 { u32 u; _Float16 h[2]; };
union AB { u32 u[4]; f16x8 v; };

__device__ __forceinline__ float f16lo(u32 v) { U32H2 a; a.u = v; return (float)a.h[0]; }
__device__ __forceinline__ float f16hi(u32 v) { U32H2 a; a.u = v; return (float)a.h[1]; }
__device__ __forceinline__ u32 packh2(float a, float b) {
    U32H2 x; x.h[0] = (_Float16)a; x.h[1] = (_Float16)b; return x.u;
}

// A*tanh(S*v), S=2/3: tanh(y) = 1 - 2/(exp(2y)+1), 2y = (4/3)v
__device__ __forceinline__ float tact(float v) {
    float e = __expf(1.3333333333f * v);
    return 1.7159f * (1.0f - 2.0f * __builtin_amdgcn_rcpf(e + 1.0f));
}

__device__ const int C3MASKBITS[16] = {0x07,0x0E,0x1C,0x38,0x31,0x23,0x0F,0x1E,
                                       0x3C,0x39,0x33,0x27,0x1B,0x36,0x2D,0x3F};

// ---------------- front: transpose + C1 + S2 via MFMA, 16 samples/block -----
// xt LDS: [row32][n16][pair16], stride 20 dw (b128-aligned, 2-way banks only).
// A_d[oc][k=ky*8+kx] = w1[oc][ky][kx-d] (4 shift variants, 2 K-chunks).
// S2P adjacent pairs: s2p[ch*98 + oy2*7 + c2][N] = (s2[oy2][2c2], s2[oy2][2c2+1]).
__global__ __launch_bounds__(256) void k_front(
    const float* __restrict__ x,
    const float* __restrict__ w1, const float* __restrict__ b1,
    const float* __restrict__ s2w, const float* __restrict__ s2b,
    u32* __restrict__ s2p)
{
    __shared__ u32 xt[10240];                // 41 KB
    const int t = threadIdx.x;
    const int n0 = blockIdx.x * 16;
    const int lane = t & 63;
    const int n = lane & 15;
    const int g = lane >> 4;                 // 0..3
    const int w = t >> 6;                    // wave id

    {   // stage: coalesced f32 read, pack f16 pairs, transpose into LDS
        const int nn = t >> 4, i = t & 15;
        const float* xg = x + (size_t)(n0 + nn) * 1024 + i * 4;
        #pragma unroll
        for (int k = 0; k < 16; ++k) {
            float4 v = *(const float4*)(xg + k * 64);
            int row = (i >> 3) + 2 * k;
            u32* dst = xt + (row * 16 + nn) * 20 + (i & 7) * 2;
            dst[0] = packh2(v.x, v.y);
            dst[1] = packh2(v.z, v.w);
        }
    }
    __syncthreads();

    // A fragments: 4 shift variants x 2 K-chunks (verified R7 layout)
    AB A[4][2];
    #pragma unroll
    for (int d = 0; d < 4; ++d)
        #pragma unroll
        for (int c = 0; c < 2; ++c)
            #pragma unroll
            for (int j = 0; j < 4; ++j) {
                int ky = c * 4 + g;
                float lo = 0.0f, hi = 0.0f;
                if (n < 6 && ky < 5) {
                    int kx0 = 2 * j, kx1 = 2 * j + 1;
                    if (kx0 >= d && kx0 - d < 5) lo = w1[n * 25 + ky * 5 + kx0 - d];
                    if (kx1 >= d && kx1 - d < 5) hi = w1[n * 25 + ky * 5 + kx1 - d];
                }
                A[d][c].u[j] = packh2(lo, hi);
            }

    float b1v[4], swv[4], sbv[4];
    #pragma unroll
    for (int r = 0; r < 4; ++r) {
        int R = g * 4 + r; int Rc = (R < 6) ? R : 0;
        b1v[r] = b1[Rc]; swv[r] = s2w[Rc]; sbv[r] = s2b[Rc];
    }

    for (int oy2 = w; oy2 < 14; oy2 += 4) {
        float pend[4];
        #pragma unroll
        for (int part = 0; part < 2; ++part) {
            const int y = 2 * oy2 + part;
            const int r0 = y + g;
            int r1 = y + 4 + g; if (r1 > 31) r1 = 31;   // ky>4 rows have A=0
            // register row cache: 16 pairs per row, 4x ds_read_b128 each
            const u32* p0p = xt + (r0 * 16 + n) * 20;
            const u32* p1p = xt + (r1 * 16 + n) * 20;
            u32x4 a0 = *(const u32x4*)(p0p),     a1 = *(const u32x4*)(p0p + 4),
                  a2 = *(const u32x4*)(p0p + 8), a3 = *(const u32x4*)(p0p + 12);
            u32x4 c0 = *(const u32x4*)(p1p),     c1 = *(const u32x4*)(p1p + 4),
                  c2 = *(const u32x4*)(p1p + 8), c3 = *(const u32x4*)(p1p + 12);
            u32 R0[16] = {a0.x,a0.y,a0.z,a0.w, a1.x,a1.y,a1.z,a1.w,
                          a2.x,a2.y,a2.z,a2.w, a3.x,a3.y,a3.z,a3.w};
            u32 R1[16] = {c0.x,c0.y,c0.z,c0.w, c1.x,c1.y,c1.z,c1.w,
                          c2.x,c2.y,c2.z,c2.w, c3.x,c3.y,c3.z,c3.w};
            #pragma unroll
            for (int qx = 0; qx < 7; ++qx) {
                AB B0, B1;
                #pragma unroll
                for (int j = 0; j < 4; ++j) {
                    B0.u[j] = R0[2 * qx + j];
                    B1.u[j] = R1[2 * qx + j];
                }
                f32x4 F[4];
                #pragma unroll
                for (int d = 0; d < 4; ++d) {
                    F[d] = (f32x4){0.0f, 0.0f, 0.0f, 0.0f};
                    F[d] = __builtin_amdgcn_mfma_f32_16x16x32_f16(A[d][0].v, B0.v, F[d], 0, 0, 0);
                    F[d] = __builtin_amdgcn_mfma_f32_16x16x32_f16(A[d][1].v, B1.v, F[d], 0, 0, 0);
                }
                const int col = part * 7 + qx;
                #pragma unroll
                for (int r = 0; r < 4; ++r) {
                    float m4 = 0.25f * (tact(F[0][r] + b1v[r]) + tact(F[1][r] + b1v[r]) +
                                        tact(F[2][r] + b1v[r]) + tact(F[3][r] + b1v[r]));
                    float sv = tact(swv[r] * m4 + sbv[r]);
                    if (col & 1) {
                        int R = g * 4 + r;
                        if (R < 6)
                            s2p[(size_t)(R * 98 + oy2 * 7 + (col >> 1)) * 16384 + n0 + n]
                                = packh2(pend[r], sv);
                    } else {
                        pend[r] = sv;
                    }
                }
            }
        }
    }
}

// ---------------- C3 + S4 via MFMA, row-register cache + dual-A -------------
// sm: [(ic*14+row)*16+n]*8 + pair (pairs 0..6 data, 7 = zero pad). 43 KB.
// A0[oc][k=(ic*5+ky)*8+kx] = w3 (aligned); A1: kx -> w3[kx-1] (shift-1).
// Even ox=2p0 uses A0, odd ox=2p0+1 uses A1, SAME B window (pairs p0..p0+3).
__global__ __launch_bounds__(256) void k_c3(
    const u32* __restrict__ s2p,
    const float* __restrict__ w3, const float* __restrict__ b3,
    const float* __restrict__ s4w, const float* __restrict__ s4b,
    _Float16* __restrict__ s4h)
{
    __shared__ u32 sm[10752];
    const int t = threadIdx.x;
    const int n0 = blockIdx.x * 16;
    const int lane = t & 63;
    const int n = lane & 15;
    const int g = lane >> 4;
    const int w = t >> 6;

    {   // zero pads + stage 588 pair-features x 16 samples
        for (int i = t; i < 1344; i += 256) sm[i * 8 + 7] = 0u;
        const int fi = t >> 4, nn = t & 15;
        #pragma unroll 4
        for (int i = 0; i < 37; ++i) {
            int f = i * 16 + fi;
            if (f < 588) {
                int ic = f / 98, rem = f % 98;
                int row = rem / 7, c2 = rem % 7;
                sm[((ic * 14 + row) * 16 + nn) * 8 + c2] = s2p[(size_t)f * 16384 + n0 + nn];
            }
        }
    }
    __syncthreads();

    // A fragments (8 K-chunks x 2 shift variants), dense-masked weights
    AB A0[8], A1[8];
    int rb[8];                               // ic*14 + ky (clamped) per chunk
    #pragma unroll
    for (int c = 0; c < 8; ++c) {
        int r = c * 4 + g;
        bool valid = (r < 30);
        int ic = valid ? r / 5 : 0, ky = valid ? r % 5 : 0;
        bool conn = valid && ((C3MASKBITS[n] >> ic) & 1);
        rb[c] = ic * 14 + ky;
        const float* wp = w3 + (n * 6 + ic) * 25 + ky * 5;
        #pragma unroll
        for (int j = 0; j < 4; ++j) {
            int kx0 = 2 * j, kx1 = 2 * j + 1;
            float lo0 = (conn && kx0 < 5) ? wp[kx0] : 0.0f;
            float hi0 = (conn && kx1 < 5) ? wp[kx1] : 0.0f;
            float lo1 = (conn && kx0 >= 1 && kx0 <= 5) ? wp[kx0 - 1] : 0.0f;
            float hi1 = (conn && kx1 <= 5) ? wp[kx1 - 1] : 0.0f;
            A0[c].u[j] = packh2(lo0, hi0);
            A1[c].u[j] = packh2(lo1, hi1);
        }
    }

    float b3v[4], s4wv[4], s4bv[4];
    #pragma unroll
    for (int r = 0; r < 4; ++r) {
        int R = g * 4 + r;
        b3v[r] = b3[R]; s4wv[r] = s4w[R]; s4bv[r] = s4b[R];
    }

    for (int y2 = w; y2 < 5; y2 += 4) {
        float part2[4];
        #pragma unroll
        for (int u = 0; u < 2; ++u) {
            f32x4 ae[5], ao[5];
            #pragma unroll
            for (int p = 0; p < 5; ++p) {
                ae[p] = (f32x4){0.0f, 0.0f, 0.0f, 0.0f};
                ao[p] = (f32x4){0.0f, 0.0f, 0.0f, 0.0f};
            }
            #pragma unroll
            for (int c = 0; c < 8; ++c) {
                const u32* bp = sm + ((rb[c] + 2 * y2 + u) * 16 + n) * 8;
                u32x4 v0 = *(const u32x4*)bp;
                u32x4 v1 = *(const u32x4*)(bp + 4);
                u32 v[8] = {v0.x, v0.y, v0.z, v0.w, v1.x, v1.y, v1.z, v1.w};
                #pragma unroll
                for (int p = 0; p < 5; ++p) {
                    AB B;
                    B.u[0] = v[p]; B.u[1] = v[p + 1];
                    B.u[2] = v[p + 2]; B.u[3] = v[p + 3];
                    ae[p] = __builtin_amdgcn_mfma_f32_16x16x32_f16(A0[c].v, B.v, ae[p], 0, 0, 0);
                    ao[p] = __builtin_amdgcn_mfma_f32_16x16x32_f16(A1[c].v, B.v, ao[p], 0, 0, 0);
                }
            }
            // tanh + reshape-flat S4 pooling (flat f = u*10 + ox)
            #pragma unroll
            for (int r = 0; r < 4; ++r) {
                float te[5], to[5];
                #pragma unroll
                for (int p = 0; p < 5; ++p) {
                    te[p] = tact(ae[p][r] + b3v[r]);
                    to[p] = tact(ao[p][r] + b3v[r]);
                }
                const int R = g * 4 + r;
                const size_t ob = (size_t)(R * 25 + y2 * 5) * 16384 + n0 + n;
                if (u == 0) {
                    float s0 = te[0] + to[0] + te[1] + to[1];
                    float s1 = te[2] + to[2] + te[3] + to[3];
                    s4h[ob]           = (_Float16)tact(0.25f * s0 * s4wv[r] + s4bv[r]);
                    s4h[ob + 16384]   = (_Float16)tact(0.25f * s1 * s4wv[r] + s4bv[r]);
                    part2[r] = te[4] + to[4];
                } else {
                    float s2v = part2[r] + te[0] + to[0];
                    float s3 = te[1] + to[1] + te[2] + to[2];
                    float s4v = te[3] + to[3] + te[4] + to[4];
                    s4h[ob + 2 * 16384] = (_Float16)tact(0.25f * s2v * s4wv[r] + s4bv[r]);
                    s4h[ob + 3 * 16384] = (_Float16)tact(0.25f * s3 * s4wv[r] + s4bv[r]);
                    s4h[ob + 4 * 16384] = (_Float16)tact(0.25f * s4v * s4wv[r] + s4bv[r]);
                }
            }
        }
    }
}

// ---------------- C5: 120-ch GEMV over flat 400, grid (64, 12) --------------
__global__ __launch_bounds__(256) void k_c5(
    const _Float16* __restrict__ s4h, const float* __restrict__ w5,
    const float* __restrict__ b5, u32* __restrict__ h5p, int nb)
{
    const int sl = blockIdx.x * 256 + threadIdx.x;
    const int chg = blockIdx.y;
    float acc[10];
    #pragma unroll
    for (int c = 0; c < 10; ++c) acc[c] = b5[chg * 10 + c];
    #pragma unroll 4
    for (int i = 0; i < 400; ++i) {
        const float v = (float)s4h[(size_t)i * nb + sl];
        #pragma unroll
        for (int c = 0; c < 10; ++c)
            acc[c] += v * w5[(size_t)(chg * 10 + c) * 400 + i];
    }
    #pragma unroll
    for (int j = 0; j < 5; ++j)
        h5p[(size_t)(chg * 5 + j) * nb + sl] =
            packh2(tact(acc[2 * j]), tact(acc[2 * j + 1]));
}

// ---------------- F6: 84-out GEMV over 60 h5 pairs, grid (64, 6) ------------
__global__ __launch_bounds__(256) void k_f6(
    const u32* __restrict__ h5p, const float* __restrict__ f6w,
    const float* __restrict__ f6b, u32* __restrict__ h6p, int nb)
{
    const int sl = blockIdx.x * 256 + threadIdx.x;
    const int og = blockIdx.y;
    float hv[120];
    #pragma unroll
    for (int i = 0; i < 60; ++i) {
        const u32 v = h5p[(size_t)i * nb + sl];
        hv[2 * i]     = f16lo(v);
        hv[2 * i + 1] = f16hi(v);
    }
    float acc[14];
    #pragma unroll
    for (int o = 0; o < 14; ++o) acc[o] = f6b[og * 14 + o];
    #pragma unroll 4
    for (int i = 0; i < 120; ++i) {
        #pragma unroll
        for (int o = 0; o < 14; ++o)
            acc[o] += hv[i] * f6w[(size_t)(og * 14 + o) * 120 + i];
    }
    #pragma unroll
    for (int j = 0; j < 7; ++j)
        h6p[(size_t)(og * 7 + j) * nb + sl] =
            packh2(tact(acc[2 * j]), tact(acc[2 * j + 1]));
}

// ---------------- RBF head, grid (64, 5) ------------------------------------
__global__ __launch_bounds__(256) void k_rbf(
    const u32* __restrict__ h6p, const float* __restrict__ rbf,
    float* __restrict__ out, int nb)
{
    const int sl = blockIdx.x * 256 + threadIdx.x;
    const int gy = blockIdx.y;
    float hv[84];
    #pragma unroll
    for (int i = 0; i < 42; ++i) {
        const u32 v = h6p[(size_t)i * nb + sl];
        hv[2 * i]     = f16lo(v);
        hv[2 * i + 1] = f16hi(v);
    }
    #pragma unroll
    for (int a = 0; a < 2; ++a) {
        const int c = 2 * gy + a;
        float acc = 0.0f;
        #pragma unroll 4
        for (int i = 0; i < 84; ++i) {
            float d = hv[i] - rbf[c * 84 + i];
            acc += d * d;
        }
        out[(size_t)sl * 10 + c] = acc;
    }
}

extern "C" void kernel_launch(void* const* d_in, const int* in_sizes, int n_in,
                              void* d_out, int out_size, void* d_ws, size_t ws_size,
                              hipStream_t stream)
{
    const float* x    = (const float*)d_in[0];
    const float* w1   = (const float*)d_in[1];
    const float* b1   = (const float*)d_in[2];
    const float* s2w  = (const float*)d_in[3];
    const float* s2b  = (const float*)d_in[4];
    const float* w3   = (const float*)d_in[5];
    const float* b3   = (const float*)d_in[6];
    const float* s4w  = (const float*)d_in[7];
    const float* s4b  = (const float*)d_in[8];
    const float* w5   = (const float*)d_in[9];
    const float* b5   = (const float*)d_in[10];
    const float* f6w  = (const float*)d_in[11];
    const float* f6b  = (const float*)d_in[12];
    const float* rbfw = (const float*)d_in[13];
    float* out = (float*)d_out;
    char* ws = (char*)d_ws;

    u32*      S2P = (u32*)(ws);
    _Float16* S4H = (_Float16*)(ws + 38535168);
    u32*      H5P = (u32*)(ws);
    u32*      H6P = (u32*)(ws + 4194304);

    k_front<<<1024, 256, 0, stream>>>(x, w1, b1, s2w, s2b, S2P);
    k_c3<<<1024, 256, 0, stream>>>(S2P, w3, b3, s4w, s4b, S4H);
    k_c5<<<dim3(64, 12), 256, 0, stream>>>(S4H, w5, b5, H5P, 16384);
    k_f6<<<dim3(64, 6), 256, 0, stream>>>(H5P, f6w, f6b, H6P, 16384);
    k_rbf<<<dim3(64, 5), 256, 0, stream>>>(H6P, rbfw, out, 16384);
}